// Round 1
// baseline (392.609 us; speedup 1.0000x reference)
//
#include <hip/hip_runtime.h>

#define BB 128
#define NN 8192
#define SS 100
#define KK 512
#define SPLIT 10                 // sample chunks per batch row
#define SPB (SS / SPLIT)         // samples per block = 10
#define NT 256                   // threads per block
#define EPT 32                   // elements per thread
#define VPT 8                    // float4 loads per thread

// One block handles (b, chunk of SPB samples). Elements are owned strided:
// thread t owns gidx = j*1024 + t*4 + c for j in [0,8), c in [0,4) -> float4
// loads are fully coalesced (256 threads * 16B = 4KB per j).
__global__ __launch_bounds__(NT) void gumbel_topk_kernel(
    const float* __restrict__ logits,
    const float* __restrict__ uniform,
    float* __restrict__ out) {

    __shared__ int hist[2048];
    __shared__ int waveTot[4];
    __shared__ int bcastSel;
    __shared__ int bcastKK;
    __shared__ int eqNum;
    __shared__ int eqList[256];

    const int tid  = threadIdx.x;
    const int lane = tid & 63;
    const int wv   = tid >> 6;
    const int b     = blockIdx.x / SPLIT;
    const int chunk = blockIdx.x % SPLIT;

    // ---- load this row's logits into registers (reused across samples)
    float lg[EPT];
    const float* lrow = logits + (size_t)b * NN;
#pragma unroll
    for (int j = 0; j < VPT; ++j) {
        const float4 v = *reinterpret_cast<const float4*>(lrow + j * 1024 + tid * 4);
        lg[j * 4 + 0] = v.x; lg[j * 4 + 1] = v.y;
        lg[j * 4 + 2] = v.z; lg[j * 4 + 3] = v.w;
    }

    int cnt[EPT];
#pragma unroll
    for (int e = 0; e < EPT; ++e) cnt[e] = 0;

    for (int si = 0; si < SPB; ++si) {
        const int s = chunk * SPB + si;
        const float* urow = uniform + ((size_t)b * SS + s) * NN;

        // ---- compute monotone uint keys of perturbed = logit + gumbel
        unsigned key[EPT];
#pragma unroll
        for (int j = 0; j < VPT; ++j) {
            const float4 v = *reinterpret_cast<const float4*>(urow + j * 1024 + tid * 4);
            float uu[4] = {v.x, v.y, v.z, v.w};
#pragma unroll
            for (int c = 0; c < 4; ++c) {
                float g = -logf(-logf(uu[c] + 1e-20f) + 1e-20f);
                float p = lg[j * 4 + c] + g;           // TAU == 1
                unsigned bits = __float_as_uint(p);
                key[j * 4 + c] = (bits & 0x80000000u) ? ~bits : (bits | 0x80000000u);
            }
        }

        // ---- radix-select the K-th largest key: passes over bits
        // [31:21] (2048 bins), [20:10] (2048 bins), [9:0] (1024 bins)
        unsigned pref = 0;
        int kk = KK;
#pragma unroll
        for (int pass = 0; pass < 3; ++pass) {
            const int shift = (pass == 0) ? 21 : (pass == 1) ? 10 : 0;
            const int nbits = (pass == 2) ? 10 : 11;
            const int bins  = 1 << nbits;
            const int bpt   = bins / NT;   // 8, 8, 4

            __syncthreads();               // previous-pass hist reads done
            for (int i = tid; i < bins; i += NT) hist[i] = 0;
            if (pass == 2 && tid == 0) eqNum = 0;
            __syncthreads();

            if (pass == 0) {
#pragma unroll
                for (int e = 0; e < EPT; ++e)
                    atomicAdd(&hist[key[e] >> 21], 1);
            } else {
                const int hs = shift + nbits;      // 21 or 10
                const unsigned hpref = pref >> hs;
#pragma unroll
                for (int e = 0; e < EPT; ++e)
                    if ((key[e] >> hs) == hpref)
                        atomicAdd(&hist[(key[e] >> shift) & (bins - 1)], 1);
            }
            __syncthreads();

            // per-thread sum of its bins (thread t owns [t*bpt, t*bpt+bpt))
            int hloc[8];
            int S = 0;
            for (int i = 0; i < bpt; ++i) { hloc[i] = hist[tid * bpt + i]; S += hloc[i]; }

            // wave-level inclusive suffix scan (no barriers)
            int suf = S;
#pragma unroll
            for (int d = 1; d < 64; d <<= 1) {
                int o = __shfl_down(suf, d);
                if (lane + d < 64) suf += o;
            }
            if (lane == 0) waveTot[wv] = suf;
            __syncthreads();

            int above = suf - S;                       // higher lanes, same wave
            for (int w2 = wv + 1; w2 < 4; ++w2) above += waveTot[w2];

            // walk own bins high -> low; the unique crossing thread broadcasts
            int cum = above;
            for (int i = bpt - 1; i >= 0; --i) {
                int h = hloc[i];
                if (cum < kk && cum + h >= kk) {
                    bcastSel = tid * bpt + i;
                    bcastKK  = kk - cum;
                }
                cum += h;
            }
            __syncthreads();
            pref |= ((unsigned)bcastSel) << shift;
            kk = bcastKK;
        }

        const unsigned Tkey = pref;   // exact K-th largest key value
        const int r = kk;             // how many ties (== Tkey) to take
        const int c_eq = hist[Tkey & 1023];   // broadcast read, still valid

        if (c_eq == r) {
            // common case: take all elements >= Tkey (exactly K of them)
#pragma unroll
            for (int e = 0; e < EPT; ++e) cnt[e] += (key[e] >= Tkey) ? 1 : 0;
        } else {
            // rare: ties at threshold; take the r smallest global indices
#pragma unroll
            for (int e = 0; e < EPT; ++e) {
                if (key[e] > Tkey) {
                    cnt[e] += 1;
                } else if (key[e] == Tkey) {
                    int pos = atomicAdd(&eqNum, 1);
                    if (pos < 256) eqList[pos] = (e >> 2) * 1024 + tid * 4 + (e & 3);
                }
            }
            __syncthreads();
            const int ne = (eqNum < 256) ? eqNum : 256;
#pragma unroll
            for (int e = 0; e < EPT; ++e) {
                if (key[e] == Tkey) {
                    const int gidx = (e >> 2) * 1024 + tid * 4 + (e & 3);
                    int rank = 0;
                    for (int x = 0; x < ne; ++x) rank += (eqList[x] < gidx) ? 1 : 0;
                    if (rank < r) cnt[e] += 1;
                }
            }
            __syncthreads();
        }
    }

    // ---- accumulate into output (out pre-zeroed by memset)
    float* orow = out + (size_t)b * NN;
#pragma unroll
    for (int e = 0; e < EPT; ++e) {
        if (cnt[e]) {
            const int gidx = (e >> 2) * 1024 + tid * 4 + (e & 3);
            atomicAdd(orow + gidx, (float)cnt[e] * 0.01f);
        }
    }
}

extern "C" void kernel_launch(void* const* d_in, const int* in_sizes, int n_in,
                              void* d_out, int out_size, void* d_ws, size_t ws_size,
                              hipStream_t stream) {
    const float* logits  = (const float*)d_in[0];   // [128, 8192] f32
    const float* uniform = (const float*)d_in[1];   // [128, 100, 8192] f32
    float* out = (float*)d_out;                     // [128, 8192] f32

    // zero the accumulator (harness poisons d_out; we accumulate atomically)
    hipMemsetAsync(out, 0, (size_t)out_size * sizeof(float), stream);

    const int grid = BB * SPLIT;   // 1280 blocks
    gumbel_topk_kernel<<<grid, NT, 0, stream>>>(logits, uniform, out);
}

// Round 2
// 294.631 us; speedup vs baseline: 1.3325x; 1.3325x over previous
//
#include <hip/hip_runtime.h>

#define BB 128
#define NN 8192
#define SS 100
#define KK 512
#define SPLIT 20                 // sample chunks per batch row
#define SPB (SS / SPLIT)         // samples per block = 5
#define NT 256                   // threads per block
#define EPT 32                   // elements per thread
#define VPT 8                    // float4 loads per thread
#define CAND 512                 // candidate list capacity (threshold bin)

// Linear monotone binning of perturbed value p into [0,2047].
// p realistically spans ~[-9, 22]; map [-12,24] -> [0,2048).
__device__ __forceinline__ int bin_of(float p) {
    const float SC = 2048.0f / 36.0f;
    const float OF = 12.0f * (2048.0f / 36.0f);
    int b = (int)fmaf(p, SC, OF);   // trunc; monotone in p
    b = b < 0 ? 0 : b;
    return b > 2047 ? 2047 : b;
}

__device__ __forceinline__ float fast_ln(float x) {
    // v_log_f32 computes log2; scale to natural log
    return __builtin_amdgcn_logf(x) * 0.69314718056f;
}

// One block handles (b, chunk of SPB samples). Thread t owns
// gidx = j*1024 + t*4 + c  (j<8, c<4) -> fully coalesced float4 loads.
__global__ __launch_bounds__(NT) void gumbel_topk_kernel(
    const float* __restrict__ logits,
    const float* __restrict__ uniform,
    float* __restrict__ out) {

    __shared__ __align__(16) int hist[2048];
    __shared__ float candKey[CAND];
    __shared__ int   candIdx[CAND];   // bit31 = selected flag
    __shared__ int   waveTot[4];
    __shared__ int   bcastSel;
    __shared__ int   bcastKK;
    __shared__ int   candCnt;

    const int tid  = threadIdx.x;
    const int lane = tid & 63;
    const int wv   = tid >> 6;
    const int b     = blockIdx.x / SPLIT;
    const int chunk = blockIdx.x % SPLIT;

    // ---- logits row into registers (reused across samples)
    float lg[EPT];
    const float* lrow = logits + (size_t)b * NN;
#pragma unroll
    for (int j = 0; j < VPT; ++j) {
        const float4 v = *reinterpret_cast<const float4*>(lrow + j * 1024 + tid * 4);
        lg[j * 4 + 0] = v.x; lg[j * 4 + 1] = v.y;
        lg[j * 4 + 2] = v.z; lg[j * 4 + 3] = v.w;
    }

    // packed per-element counters: 4 x 8-bit per register (max count SPB=5)
    unsigned cnt4[EPT / 4];
#pragma unroll
    for (int i = 0; i < EPT / 4; ++i) cnt4[i] = 0;

    for (int si = 0; si < SPB; ++si) {
        const int s = chunk * SPB + si;
        const float* urow = uniform + ((size_t)b * SS + s) * NN;

        // ---- perturbed values p = logit + gumbel(u), fast log path
        float p[EPT];
#pragma unroll
        for (int j = 0; j < VPT; ++j) {
            const float4 v = *reinterpret_cast<const float4*>(urow + j * 1024 + tid * 4);
            float uu[4] = {v.x, v.y, v.z, v.w};
#pragma unroll
            for (int c = 0; c < 4; ++c) {
                const float u = uu[c] + 1e-20f;
                const float w = -fast_ln(u) + 1e-20f;   // -log(u+eps)+eps
                const float g = -fast_ln(w);            // gumbel
                p[j * 4 + c] = lg[j * 4 + c] + g;       // TAU == 1
            }
        }

        // ---- zero histogram (prev sample's LDS reads are done: barrier)
        __syncthreads();
        {
            const int4 z = make_int4(0, 0, 0, 0);
            reinterpret_cast<int4*>(hist)[tid]       = z;
            reinterpret_cast<int4*>(hist)[tid + 256] = z;
        }
        if (tid == 0) candCnt = 0;
        __syncthreads();

        // ---- single histogram pass (near-uniform bins -> few conflicts)
#pragma unroll
        for (int e = 0; e < EPT; ++e)
            atomicAdd(&hist[bin_of(p[e])], 1);
        __syncthreads();

        // ---- find bin containing the K-th largest (suffix scan hi->lo)
        int hloc[8];
        int sum = 0;
        const int base = tid * 8;
#pragma unroll
        for (int i = 0; i < 8; ++i) { hloc[i] = hist[base + i]; sum += hloc[i]; }

        int suf = sum;   // inclusive suffix sum within wave (higher lane = higher bins)
#pragma unroll
        for (int d = 1; d < 64; d <<= 1) {
            const int o = __shfl_down(suf, d);
            if (lane + d < 64) suf += o;
        }
        if (lane == 0) waveTot[wv] = suf;
        __syncthreads();

        int above = suf - sum;
        for (int w2 = wv + 1; w2 < 4; ++w2) above += waveTot[w2];

        int cum = above;
#pragma unroll
        for (int i = 7; i >= 0; --i) {
            const int h = hloc[i];
            if (cum < KK && cum + h >= KK) { bcastSel = base + i; bcastKK = KK - cum; }
            cum += h;
        }
        __syncthreads();
        const int selBin = bcastSel;
        const int kk     = bcastKK;     // how many to take from selBin

        // ---- collect threshold-bin candidates
#pragma unroll
        for (int e = 0; e < EPT; ++e) {
            if (bin_of(p[e]) == selBin) {
                const int pos = atomicAdd(&candCnt, 1);
                if (pos < CAND) {
                    candKey[pos] = p[e];
                    candIdx[pos] = (e >> 2) * 1024 + tid * 4 + (e & 3);
                }
            }
        }
        __syncthreads();

        // ---- wave0: exact ranks (key desc, index asc = JAX tie-break)
        const int c = candCnt < CAND ? candCnt : CAND;
        if (wv == 0) {
            for (int l = lane; l < c; l += 64) {
                const float kl = candKey[l];
                const int   il = candIdx[l] & 0x7FFFFFFF;
                int rank = 0;
                for (int j = 0; j < c; ++j) {
                    const float kj = candKey[j];
                    const int   ij = candIdx[j] & 0x7FFFFFFF;
                    rank += (kj > kl || (kj == kl && ij < il)) ? 1 : 0;
                }
                if (rank < kk) candIdx[l] |= 0x80000000;  // word store; readers mask
            }
        }
        __syncthreads();

        // ---- membership update
#pragma unroll
        for (int e = 0; e < EPT; ++e) {
            const int bb = bin_of(p[e]);
            if (bb > selBin) {
                cnt4[e >> 2] += (1u << ((e & 3) * 8));
            } else if (bb == selBin) {
                const int gidx = (e >> 2) * 1024 + tid * 4 + (e & 3);
                for (int j = 0; j < c; ++j) {
                    if ((candIdx[j] & 0x7FFFFFFF) == gidx) {
                        if (candIdx[j] & 0x80000000u)
                            cnt4[e >> 2] += (1u << ((e & 3) * 8));
                        break;
                    }
                }
            }
        }
    }

    // ---- accumulate into output (out pre-zeroed by memset)
    float* orow = out + (size_t)b * NN;
#pragma unroll
    for (int e = 0; e < EPT; ++e) {
        const unsigned cc = (cnt4[e >> 2] >> ((e & 3) * 8)) & 0xFFu;
        if (cc) {
            const int gidx = (e >> 2) * 1024 + tid * 4 + (e & 3);
            atomicAdd(orow + gidx, (float)cc * 0.01f);
        }
    }
}

extern "C" void kernel_launch(void* const* d_in, const int* in_sizes, int n_in,
                              void* d_out, int out_size, void* d_ws, size_t ws_size,
                              hipStream_t stream) {
    const float* logits  = (const float*)d_in[0];   // [128, 8192] f32
    const float* uniform = (const float*)d_in[1];   // [128, 100, 8192] f32
    float* out = (float*)d_out;                     // [128, 8192] f32

    hipMemsetAsync(out, 0, (size_t)out_size * sizeof(float), stream);

    const int grid = BB * SPLIT;   // 2560 blocks
    gumbel_topk_kernel<<<grid, NT, 0, stream>>>(logits, uniform, out);
}

// Round 3
// 155.391 us; speedup vs baseline: 2.5266x; 1.8961x over previous
//
#include <hip/hip_runtime.h>

#define BB 128
#define NN 8192
#define SS 100
#define KK 512
#define SPLIT 25                 // sample chunks per batch row
#define SPB (SS / SPLIT)         // samples per block = 4
#define NT 512                   // threads per block
#define EPT 16                   // elements per thread
#define VPT 4                    // float4 loads per thread
#define CAND 512                 // candidate list capacity (threshold bin)
#define NBIN 2048
#define BPT (NBIN / NT)          // bins per thread = 4
#define NWAVE (NT / 64)          // 8

// Linear monotone binning of p into [0,2047]; exactness does not depend on
// the range (clamped bins are handled by exact in-bin ranking).
__device__ __forceinline__ int bin_of(float p) {
    const float SC = 2048.0f / 36.0f;
    const float OF = 12.0f * SC;
    int b = (int)fmaf(p, SC, OF);
    b = b < 0 ? 0 : b;
    return b > 2047 ? 2047 : b;
}

__device__ __forceinline__ float fast_ln(float x) {
    return __builtin_amdgcn_logf(x) * 0.69314718056f;   // v_log_f32 * ln2
}

// MODE 0: write packed-u8 partial counts to ws. MODE 1: atomicAdd into out.
template <int MODE>
__global__ __launch_bounds__(NT) void gumbel_topk_kernel(
    const float* __restrict__ logits,
    const float* __restrict__ uniform,
    void* __restrict__ sink) {

    __shared__ __align__(16) int hist[2][NBIN];   // waves 0-3 / waves 4-7
    __shared__ float candKey[CAND];
    __shared__ int   candIdx[CAND];
    __shared__ int   waveTot[NWAVE];
    __shared__ int   bcastSel;
    __shared__ int   bcastKK;
    __shared__ int   candCnt;

    const int tid  = threadIdx.x;
    const int lane = tid & 63;
    const int wv   = tid >> 6;
    const int half = wv >> 2;
    const int b     = blockIdx.x / SPLIT;
    const int chunk = blockIdx.x % SPLIT;

    // ---- logits row chunk into registers (reused across samples)
    float lg[EPT];
    const float* lrow = logits + (size_t)b * NN;
#pragma unroll
    for (int j = 0; j < VPT; ++j) {
        const float4 v = *reinterpret_cast<const float4*>(lrow + j * 2048 + tid * 4);
        lg[j * 4 + 0] = v.x; lg[j * 4 + 1] = v.y;
        lg[j * 4 + 2] = v.z; lg[j * 4 + 3] = v.w;
    }

    // packed per-element counters: 4 x u8 per register (max count SPB=4)
    unsigned cnt4[VPT];
#pragma unroll
    for (int i = 0; i < VPT; ++i) cnt4[i] = 0;

    // ---- initial histogram zero
    {
        const int4 z = make_int4(0, 0, 0, 0);
        *reinterpret_cast<int4*>(&hist[0][tid * 4]) = z;
        *reinterpret_cast<int4*>(&hist[1][tid * 4]) = z;
    }
    __syncthreads();

    const int s0 = chunk * SPB;

    auto loadSample = [&](float (&dst)[EPT], int s) {
        const float* urow = uniform + ((size_t)b * SS + s) * NN;
#pragma unroll
        for (int j = 0; j < VPT; ++j) {
            const float4 v = *reinterpret_cast<const float4*>(urow + j * 2048 + tid * 4);
            dst[j * 4 + 0] = v.x; dst[j * 4 + 1] = v.y;
            dst[j * 4 + 2] = v.z; dst[j * 4 + 3] = v.w;
        }
    };

    auto processSample = [&](float (&cur)[EPT]) {
        // p = logit + gumbel, in place (loads for next sample stay in flight)
#pragma unroll
        for (int e = 0; e < EPT; ++e) {
            const float u = cur[e] + 1e-20f;
            const float w = -fast_ln(u) + 1e-20f;
            cur[e] = lg[e] - fast_ln(w);
        }
        // A: histogram (hist zeroed by previous sample's scan phase)
#pragma unroll
        for (int e = 0; e < EPT; ++e)
            atomicAdd(&hist[half][bin_of(cur[e])], 1);
        __syncthreads();                                   // s1

        // B1: read own bins (both halves), zero them, wave suffix scan
        const int base = tid * BPT;
        int hloc[BPT];
        int sum = 0;
        {
            const int4 h0 = *reinterpret_cast<const int4*>(&hist[0][base]);
            const int4 h1 = *reinterpret_cast<const int4*>(&hist[1][base]);
            hloc[0] = h0.x + h1.x; hloc[1] = h0.y + h1.y;
            hloc[2] = h0.z + h1.z; hloc[3] = h0.w + h1.w;
            const int4 z = make_int4(0, 0, 0, 0);
            *reinterpret_cast<int4*>(&hist[0][base]) = z;
            *reinterpret_cast<int4*>(&hist[1][base]) = z;
            sum = hloc[0] + hloc[1] + hloc[2] + hloc[3];
        }
        int suf = sum;   // inclusive suffix sum within wave
#pragma unroll
        for (int d = 1; d < 64; d <<= 1) {
            const int o = __shfl_down(suf, d);
            if (lane + d < 64) suf += o;
        }
        if (lane == 0) waveTot[wv] = suf;
        __syncthreads();                                   // s2

        // B2: locate threshold bin, broadcast
        int above = suf - sum;
        for (int w2 = wv + 1; w2 < NWAVE; ++w2) above += waveTot[w2];
        int cum = above;
#pragma unroll
        for (int i = BPT - 1; i >= 0; --i) {
            const int h = hloc[i];
            if (cum < KK && cum + h >= KK) { bcastSel = base + i; bcastKK = KK - cum; }
            cum += h;
        }
        if (tid == 0) candCnt = 0;
        __syncthreads();                                   // s3

        const int selBin = bcastSel;
        const int kk     = bcastKK;

        // C: collect threshold-bin candidates
#pragma unroll
        for (int e = 0; e < EPT; ++e) {
            if (bin_of(cur[e]) == selBin) {
                const int pos = atomicAdd(&candCnt, 1);
                if (pos < CAND) {
                    candKey[pos] = cur[e];
                    candIdx[pos] = (e >> 2) * 2048 + tid * 4 + (e & 3);
                }
            }
        }
        __syncthreads();                                   // s4

        // E: membership update; in-bin elements rank themselves inline
        const int c = candCnt < CAND ? candCnt : CAND;
#pragma unroll
        for (int e = 0; e < EPT; ++e) {
            const int bb = bin_of(cur[e]);
            if (bb > selBin) {
                cnt4[e >> 2] += 1u << ((e & 3) * 8);
            } else if (bb == selBin) {
                const float kl = cur[e];
                const int   il = (e >> 2) * 2048 + tid * 4 + (e & 3);
                int rank = 0;
                for (int j = 0; j < c; ++j) {
                    const float kj = candKey[j];
                    const int   ij = candIdx[j];
                    rank += (kj > kl || (kj == kl && ij < il)) ? 1 : 0;
                }
                if (rank < kk) cnt4[e >> 2] += 1u << ((e & 3) * 8);
            }
        }
        // no sync needed: next phase-A touches only hist (quiet since B1)
    };

    float bufA[EPT], bufB[EPT];
    loadSample(bufA, s0 + 0);
    loadSample(bufB, s0 + 1);       // in flight during sample 0
    processSample(bufA);
    loadSample(bufA, s0 + 2);       // in flight during sample 1
    processSample(bufB);
    loadSample(bufB, s0 + 3);       // in flight during sample 2
    processSample(bufA);
    processSample(bufB);

    if (MODE == 0) {
        // coalesced packed-u8 partial counts; byte i == element i of this block
        unsigned* wsrow = reinterpret_cast<unsigned*>(sink) + (size_t)blockIdx.x * (NN / 4);
#pragma unroll
        for (int j = 0; j < VPT; ++j) wsrow[j * NT + tid] = cnt4[j];
    } else {
        float* orow = reinterpret_cast<float*>(sink) + (size_t)b * NN;
#pragma unroll
        for (int e = 0; e < EPT; ++e) {
            const unsigned cc = (cnt4[e >> 2] >> ((e & 3) * 8)) & 0xFFu;
            if (cc) {
                const int gidx = (e >> 2) * 2048 + tid * 4 + (e & 3);
                atomicAdd(orow + gidx, (float)cc * 0.01f);
            }
        }
    }
}

// Sum SPLIT packed-u8 partials per dword (max 4*25=100 per byte: no carry),
// scale by 0.01, write float4. One thread per dword.
__global__ __launch_bounds__(256) void reduce_kernel(
    const unsigned* __restrict__ ws, float* __restrict__ out) {
    const int d  = blockIdx.x * 256 + threadIdx.x;   // dword id, 0..262143
    const int b  = d >> 11;
    const int dn = d & 2047;
    unsigned acc = 0;
#pragma unroll
    for (int ch = 0; ch < SPLIT; ++ch)
        acc += ws[((size_t)(b * SPLIT + ch) << 11) + dn];
    float4 o;
    o.x = (float)(acc & 255u) * 0.01f;
    o.y = (float)((acc >> 8) & 255u) * 0.01f;
    o.z = (float)((acc >> 16) & 255u) * 0.01f;
    o.w = (float)(acc >> 24) * 0.01f;
    *reinterpret_cast<float4*>(out + ((size_t)d << 2)) = o;
}

extern "C" void kernel_launch(void* const* d_in, const int* in_sizes, int n_in,
                              void* d_out, int out_size, void* d_ws, size_t ws_size,
                              hipStream_t stream) {
    const float* logits  = (const float*)d_in[0];   // [128, 8192] f32
    const float* uniform = (const float*)d_in[1];   // [128, 100, 8192] f32
    float* out = (float*)d_out;                     // [128, 8192] f32

    const int grid = BB * SPLIT;                    // 3200 blocks
    const size_t need = (size_t)grid * NN;          // 26.2 MB of u8 partials

    if (ws_size >= need) {
        gumbel_topk_kernel<0><<<grid, NT, 0, stream>>>(logits, uniform, d_ws);
        reduce_kernel<<<(BB * NN / 4) / 256, 256, 0, stream>>>(
            (const unsigned*)d_ws, out);
    } else {
        hipMemsetAsync(out, 0, (size_t)out_size * sizeof(float), stream);
        gumbel_topk_kernel<1><<<grid, NT, 0, stream>>>(logits, uniform, d_out);
    }
}

// Round 4
// 143.654 us; speedup vs baseline: 2.7330x; 1.0817x over previous
//
#include <hip/hip_runtime.h>

#define BB 128
#define NN 8192
#define SS 100
#define KK 512
#define SPLIT 25                 // sample chunks per batch row
#define SPB (SS / SPLIT)         // samples per block = 4
#define NT 1024                  // threads per block (16 waves)
#define EPT 8                    // elements per thread
#define VPT 2                    // float4 loads per thread
#define CAND 512                 // candidate list capacity (threshold bin)
#define NBIN 2048
#define BPT (NBIN / NT)          // bins per thread = 2
#define NWAVE (NT / 64)          // 16

// Linear monotone binning of p into [0,2047]; exactness does not depend on
// the range (clamped bins are handled by exact in-bin ranking).
__device__ __forceinline__ int bin_of(float p) {
    const float SC = 2048.0f / 36.0f;
    const float OF = 12.0f * SC;
    int b = (int)fmaf(p, SC, OF);
    b = b < 0 ? 0 : b;
    return b > 2047 ? 2047 : b;
}

__device__ __forceinline__ float fast_ln(float x) {
    return __builtin_amdgcn_logf(x) * 0.69314718056f;   // v_log_f32 * ln2
}

// MODE 0: write packed-u8 partial counts to ws. MODE 1: atomicAdd into out.
template <int MODE>
__global__ __launch_bounds__(NT, 8) void gumbel_topk_kernel(
    const float* __restrict__ logits,
    const float* __restrict__ uniform,
    void* __restrict__ sink) {

    __shared__ __align__(16) int hist[2][NBIN];   // waves 0-7 / waves 8-15
    __shared__ float candKey[CAND];
    __shared__ int   candIdx[CAND];
    __shared__ int   waveTot[NWAVE];
    __shared__ int   bcastSel;
    __shared__ int   bcastKK;
    __shared__ int   candCnt;

    const int tid  = threadIdx.x;
    const int lane = tid & 63;
    const int wv   = tid >> 6;
    const int half = wv >> 3;
    const int b     = blockIdx.x / SPLIT;
    const int chunk = blockIdx.x % SPLIT;

    // ---- logits row chunk into registers (reused across samples)
    float lg[EPT];
    const float* lrow = logits + (size_t)b * NN;
#pragma unroll
    for (int j = 0; j < VPT; ++j) {
        const float4 v = *reinterpret_cast<const float4*>(lrow + j * 4096 + tid * 4);
        lg[j * 4 + 0] = v.x; lg[j * 4 + 1] = v.y;
        lg[j * 4 + 2] = v.z; lg[j * 4 + 3] = v.w;
    }

    // packed per-element counters: 4 x u8 per register (max count SPB=4)
    unsigned cnt4[VPT];
#pragma unroll
    for (int i = 0; i < VPT; ++i) cnt4[i] = 0;

    // ---- initial histogram zero: 4096 ints / 1024 threads = one int4 each
    *reinterpret_cast<int4*>(&hist[0][tid * 4]) = make_int4(0, 0, 0, 0);
    __syncthreads();

    const int s0 = chunk * SPB;

    auto loadSample = [&](float (&dst)[EPT], int s) {
        const float* urow = uniform + ((size_t)b * SS + s) * NN;
#pragma unroll
        for (int j = 0; j < VPT; ++j) {
            const float4 v = *reinterpret_cast<const float4*>(urow + j * 4096 + tid * 4);
            dst[j * 4 + 0] = v.x; dst[j * 4 + 1] = v.y;
            dst[j * 4 + 2] = v.z; dst[j * 4 + 3] = v.w;
        }
    };

    auto processSample = [&](float (&cur)[EPT]) {
        // p = logit + gumbel, in place (next sample's loads stay in flight)
#pragma unroll
        for (int e = 0; e < EPT; ++e) {
            const float u = cur[e] + 1e-20f;
            const float w = -fast_ln(u) + 1e-20f;
            cur[e] = lg[e] - fast_ln(w);
        }
        // A: histogram (hist zeroed by previous sample's B1 phase)
#pragma unroll
        for (int e = 0; e < EPT; ++e)
            atomicAdd(&hist[half][bin_of(cur[e])], 1);
        __syncthreads();                                   // s1

        // B1: read own bins (both halves), zero them, wave suffix scan
        const int base = tid * BPT;
        int hloc[BPT];
        int sum;
        {
            const int2 h0 = *reinterpret_cast<const int2*>(&hist[0][base]);
            const int2 h1 = *reinterpret_cast<const int2*>(&hist[1][base]);
            hloc[0] = h0.x + h1.x; hloc[1] = h0.y + h1.y;
            const int2 z = make_int2(0, 0);
            *reinterpret_cast<int2*>(&hist[0][base]) = z;
            *reinterpret_cast<int2*>(&hist[1][base]) = z;
            sum = hloc[0] + hloc[1];
        }
        int suf = sum;   // inclusive suffix sum within wave
#pragma unroll
        for (int d = 1; d < 64; d <<= 1) {
            const int o = __shfl_down(suf, d);
            if (lane + d < 64) suf += o;
        }
        if (lane == 0) waveTot[wv] = suf;
        __syncthreads();                                   // s2

        // B2: locate threshold bin, broadcast
        int above = suf - sum;
        for (int w2 = wv + 1; w2 < NWAVE; ++w2) above += waveTot[w2];
        int cum = above;
#pragma unroll
        for (int i = BPT - 1; i >= 0; --i) {
            const int h = hloc[i];
            if (cum < KK && cum + h >= KK) { bcastSel = base + i; bcastKK = KK - cum; }
            cum += h;
        }
        if (tid == 0) candCnt = 0;
        __syncthreads();                                   // s3

        const int selBin = bcastSel;
        const int kk     = bcastKK;

        // C: collect threshold-bin candidates
#pragma unroll
        for (int e = 0; e < EPT; ++e) {
            if (bin_of(cur[e]) == selBin) {
                const int pos = atomicAdd(&candCnt, 1);
                if (pos < CAND) {
                    candKey[pos] = cur[e];
                    candIdx[pos] = (e >> 2) * 4096 + tid * 4 + (e & 3);
                }
            }
        }
        __syncthreads();                                   // s4

        // E: membership update; in-bin elements rank themselves inline
        const int c = candCnt < CAND ? candCnt : CAND;
#pragma unroll
        for (int e = 0; e < EPT; ++e) {
            const int bb = bin_of(cur[e]);
            if (bb > selBin) {
                cnt4[e >> 2] += 1u << ((e & 3) * 8);
            } else if (bb == selBin) {
                const float kl = cur[e];
                const int   il = (e >> 2) * 4096 + tid * 4 + (e & 3);
                int rank = 0;
                for (int j = 0; j < c; ++j) {
                    const float kj = candKey[j];
                    const int   ij = candIdx[j];
                    rank += (kj > kl || (kj == kl && ij < il)) ? 1 : 0;
                }
                if (rank < kk) cnt4[e >> 2] += 1u << ((e & 3) * 8);
            }
        }
        // no sync needed: next phase-A touches only hist (quiet since B1)
    };

    float bufA[EPT], bufB[EPT];
    loadSample(bufA, s0 + 0);
    loadSample(bufB, s0 + 1);       // in flight during sample 0
    processSample(bufA);
    loadSample(bufA, s0 + 2);       // in flight during sample 1
    processSample(bufB);
    loadSample(bufB, s0 + 3);       // in flight during sample 2
    processSample(bufA);
    processSample(bufB);

    if (MODE == 0) {
        // coalesced packed-u8 partial counts; dword d covers gidx [4d,4d+3]
        unsigned* wsrow = reinterpret_cast<unsigned*>(sink) + (size_t)blockIdx.x * (NN / 4);
#pragma unroll
        for (int j = 0; j < VPT; ++j) wsrow[j * NT + tid] = cnt4[j];
    } else {
        float* orow = reinterpret_cast<float*>(sink) + (size_t)b * NN;
#pragma unroll
        for (int e = 0; e < EPT; ++e) {
            const unsigned cc = (cnt4[e >> 2] >> ((e & 3) * 8)) & 0xFFu;
            if (cc) {
                const int gidx = (e >> 2) * 4096 + tid * 4 + (e & 3);
                atomicAdd(orow + gidx, (float)cc * 0.01f);
            }
        }
    }
}

// Sum SPLIT packed-u8 partials per dword (max 4*25=100 per byte: no carry),
// scale by 0.01, write float4. One thread per output dword-group.
__global__ __launch_bounds__(256) void reduce_kernel(
    const unsigned* __restrict__ ws, float* __restrict__ out) {
    const int d  = blockIdx.x * 256 + threadIdx.x;   // dword id, 0..262143
    const int b  = d >> 11;
    const int dn = d & 2047;
    unsigned acc = 0;
#pragma unroll
    for (int ch = 0; ch < SPLIT; ++ch)
        acc += ws[((size_t)(b * SPLIT + ch) << 11) + dn];
    float4 o;
    o.x = (float)(acc & 255u) * 0.01f;
    o.y = (float)((acc >> 8) & 255u) * 0.01f;
    o.z = (float)((acc >> 16) & 255u) * 0.01f;
    o.w = (float)(acc >> 24) * 0.01f;
    *reinterpret_cast<float4*>(out + ((size_t)d << 2)) = o;
}

extern "C" void kernel_launch(void* const* d_in, const int* in_sizes, int n_in,
                              void* d_out, int out_size, void* d_ws, size_t ws_size,
                              hipStream_t stream) {
    const float* logits  = (const float*)d_in[0];   // [128, 8192] f32
    const float* uniform = (const float*)d_in[1];   // [128, 100, 8192] f32
    float* out = (float*)d_out;                     // [128, 8192] f32

    const int grid = BB * SPLIT;                    // 3200 blocks
    const size_t need = (size_t)grid * NN;          // 26.2 MB of u8 partials

    if (ws_size >= need) {
        gumbel_topk_kernel<0><<<grid, NT, 0, stream>>>(logits, uniform, d_ws);
        reduce_kernel<<<(BB * NN / 4) / 256, 256, 0, stream>>>(
            (const unsigned*)d_ws, out);
    } else {
        hipMemsetAsync(out, 0, (size_t)out_size * sizeof(float), stream);
        gumbel_topk_kernel<1><<<grid, NT, 0, stream>>>(logits, uniform, d_out);
    }
}